// Round 4
// baseline (6455.070 us; speedup 1.0000x reference)
//
#include <hip/hip_runtime.h>
#include <math.h>

typedef __bf16 bf16;
typedef unsigned long long ull;
typedef __attribute__((ext_vector_type(8))) __bf16 bf16x8;
typedef __attribute__((ext_vector_type(4))) float f32x4;

__global__ __launch_bounds__(256) void k_zero(unsigned* __restrict__ p, int n) {
  int i = blockIdx.x * 256 + threadIdx.x;
  if (i < n) p[i] = 0u;
}

// Gate-interleaved packed weights:
//   WT[row][k],  row = (j>>2)*16 + g*4 + (j&3),  j in [0,1024), g in [0,4)
// so that MFMA B-fragment n-index = g*4 + (j&3) within a wave's 4-column slice.
__global__ __launch_bounds__(256) void k_wt(const float* __restrict__ Wf,
                                            const float* __restrict__ Wi,
                                            const float* __restrict__ Wc,
                                            const float* __restrict__ Wo,
                                            bf16* __restrict__ WT) {
  __shared__ __align__(16) float tile[64][68];
  int g = blockIdx.z;
  const float* src = g == 0 ? Wf : g == 1 ? Wi : g == 2 ? Wc : Wo;
  int t = threadIdx.x;
  int r0 = blockIdx.x * 64, c0 = blockIdx.y * 64;   // r: k (1536), c: j (1024)
  int r = t >> 2, cs = (t & 3) * 16;
  const f32x4* s = (const f32x4*)(src + (size_t)(r0 + r) * 1024 + c0 + cs);
#pragma unroll
  for (int i = 0; i < 4; i++) *(f32x4*)&tile[r][cs + i * 4] = s[i];
  __syncthreads();
  int c = t >> 2, rs = (t & 3) * 16;
  bf16x8 v0, v1;
#pragma unroll
  for (int i = 0; i < 8; i++) v0[i] = (bf16)tile[rs + i][c];
#pragma unroll
  for (int i = 0; i < 8; i++) v1[i] = (bf16)tile[rs + 8 + i][c];
  int j = c0 + c;
  size_t row = (size_t)(j >> 2) * 16 + g * 4 + (j & 3);
  bf16* d = WT + row * 1536 + r0 + rs;
  *(bf16x8*)d       = v0;
  *(bf16x8*)(d + 8) = v1;
}

__global__ __launch_bounds__(256) void k_cvt(const float* __restrict__ src,
                                             bf16* __restrict__ dst) {
  size_t i = ((size_t)blockIdx.x * 256 + threadIdx.x) * 8;
  f32x4 a = *(const f32x4*)(src + i);
  f32x4 b = *(const f32x4*)(src + i + 4);
  bf16x8 o;
#pragma unroll
  for (int r = 0; r < 4; r++) { o[r] = (bf16)a[r]; o[4 + r] = (bf16)b[r]; }
  *(bf16x8*)(dst + i) = o;
}

// ---------------------------------------------------------------------------
// Persistent LSTM.  256 blocks = 4 batch-groups x 64 column-owner blocks.
// Wave w owns columns j0 + w*4 .. +4, ALL 4 gates (n = gate*4 + col).
//
// Round-4: R1 schedule + flags EXACTLY (per-BLOCK dword flags stored by t0
// after S_c; poll = 1 dword per lane).  Single change: the h-slab read is
// now L2-CACHED:
//   * poll flag (atomic, L2-bypassing — unchanged)
//   * __builtin_amdgcn_fence(ACQUIRE, "agent")  -> s_waitcnt + buffer_inv:
//     discards any stale L2/L1 copies of the slab cached at step ts-2
//   * PLAIN 16B loads of the slab (global_load_dwordx4, L2-cacheable).
//     Concurrent same-line misses from the ~8 same-XCD blocks of this group
//     MSHR-merge in L2 -> ~8x fewer LLC data transactions per step, and
//     half the load instructions (16B vs 2x8B atomics).
// Correctness: producer ordering is enforced by its vmcnt(0) BEFORE the
// flag store (publish stores are agent-scope, write-through to LLC), so
// once the flag is seen, fresh data is in LLC; the acquire fence guarantees
// no stale local-cache line can satisfy the subsequent plain loads.  A
// sibling block's later buffer_inv can only force a re-fetch of fresh data,
// never staleness.  R2/R3 lesson applied: flag layout/traffic untouched.
// ---------------------------------------------------------------------------
__global__ __launch_bounds__(256, 1) void k_lstm(const int* __restrict__ ids,
                                                 const bf16* __restrict__ embB,
                                                 const bf16* __restrict__ WT,
                                                 const float* __restrict__ bfp,
                                                 const float* __restrict__ bip,
                                                 const float* __restrict__ bcp,
                                                 const float* __restrict__ bop,
                                                 bf16* __restrict__ hbuf,
                                                 unsigned* __restrict__ flags_all) {
  int blk = blockIdx.x;
  int gb = blk >> 6, wgid = blk & 63, j0 = wgid * 16;
  int t = threadIdx.x, l = t & 63, w = t >> 6;
  int q = l >> 4, rl = l & 15;
  __shared__ __align__(16) bf16 sx[16 * 520];
  __shared__ __align__(16) bf16 sh[16 * 1032];
  __shared__ __align__(16) bf16 hw[4][16][4];

  // weights: packed row = (wgid*4 + w)*16 + rl
  const bf16* wrow = WT + ((size_t)(wgid * 4 + w) * 16 + rl) * 1536;
  bf16x8 wx[16], wh[32];
#pragma unroll
  for (int ks = 0; ks < 16; ++ks) wx[ks] = *(const bf16x8*)(wrow + ks * 32 + q * 8);
#pragma unroll
  for (int ks = 0; ks < 32; ++ks) wh[ks] = *(const bf16x8*)(wrow + 512 + ks * 32 + q * 8);

  int gate = rl >> 2;
  int jcol = j0 + w * 4 + (rl & 3);
  const float* bias_p = gate == 0 ? bfp : gate == 1 ? bip : gate == 2 ? bcp : bop;
  float bv = bias_p[jcol];

  unsigned* flags = flags_all + gb * 64;
  float creg[4] = {0.f, 0.f, 0.f, 0.f};

  // per-thread x-staging geometry: 4 chunks, chunk i at c = i*256 + t
  int xmm[4], xkc[4];
#pragma unroll
  for (int i = 0; i < 4; i++) { int c = i * 256 + t; xmm[i] = c >> 6; xkc[i] = c & 63; }

  int toks[4];
#pragma unroll
  for (int i = 0; i < 4; i++) toks[i] = ids[(gb * 16 + xmm[i]) * 512 + 0];

  // ---- prologue: stage x(0), compute its MFMAs ----
  f32x4 xa0 = {0.f, 0.f, 0.f, 0.f}, xa1 = {0.f, 0.f, 0.f, 0.f};
#pragma unroll
  for (int i = 0; i < 4; i++)
    *(bf16x8*)(sx + xmm[i] * 520 + xkc[i] * 8) =
        *(const bf16x8*)(embB + (size_t)toks[i] * 512 + xkc[i] * 8);
#pragma unroll
  for (int i = 0; i < 4; i++) toks[i] = ids[(gb * 16 + xmm[i]) * 512 + 1];
  __syncthreads();
  {
    const bf16* xrow = sx + rl * 520;
#pragma unroll
    for (int ks = 0; ks < 16; ks += 2) {
      bf16x8 a0 = *(const bf16x8*)(xrow + ks * 32 + q * 8);
      bf16x8 a1 = *(const bf16x8*)(xrow + (ks + 1) * 32 + q * 8);
      xa0 = __builtin_amdgcn_mfma_f32_16x16x32_bf16(a0, wx[ks], xa0, 0, 0, 0);
      xa1 = __builtin_amdgcn_mfma_f32_16x16x32_bf16(a1, wx[ks + 1], xa1, 0, 0, 0);
    }
  }
  __syncthreads();   // protect sx before iter-0 overwrite

  for (int ts = 0; ts < 512; ++ts) {
    const bf16* rbuf = hbuf + (ts & 1) * 65536;
    bf16* wbuf = hbuf + ((ts + 1) & 1) * 65536;

    // (1) issue x(ts+1) loads — flag-independent, in flight over poll
    bf16x8 xr[4];
    if (ts < 511) {
#pragma unroll
      for (int i = 0; i < 4; i++)
        xr[i] = *(const bf16x8*)(embB + (size_t)toks[i] * 512 + xkc[i] * 8);
    }

    // (2) poll per-BLOCK flags (R1 shape: 1 dword per lane), then acquire
    //     fence so the plain slab loads can't hit stale L2/L1 lines.
    if (ts > 0) {
      unsigned tgt = (unsigned)ts;
      for (;;) {
        unsigned v = __hip_atomic_load(flags + l, __ATOMIC_RELAXED,
                                       __HIP_MEMORY_SCOPE_AGENT);
        if (__ballot(v >= tgt) == ~0ull) break;
        __builtin_amdgcn_s_sleep(1);
      }
      __builtin_amdgcn_fence(__ATOMIC_ACQUIRE, "agent");
    }

    // (3) h slab [16][1024] -> regs, PLAIN 16B loads (L2-cacheable,
    //     MSHR-merged across same-XCD blocks)
    bf16x8 hr[8];
#pragma unroll
    for (int i = 0; i < 8; i++) {
      int chunk = i * 256 + t;                       // 16B chunks
      int mm = chunk >> 7, kc8 = (chunk & 127) * 8;  // bf16 units
      hr[i] = *(const bf16x8*)(rbuf + (size_t)(gb * 16 + mm) * 1024 + kc8);
    }

    // (4) prefetch token ids for ts+2
    if (ts < 510) {
#pragma unroll
      for (int i = 0; i < 4; i++) toks[i] = ids[(gb * 16 + xmm[i]) * 512 + ts + 2];
    }

    // (5) regs -> LDS
#pragma unroll
    for (int i = 0; i < 8; i++) {
      int chunk = i * 256 + t;
      int mm = chunk >> 7, kc8 = (chunk & 127) * 8;
      *(bf16x8*)(sh + mm * 1032 + kc8) = hr[i];
    }
    if (ts < 511) {
#pragma unroll
      for (int i = 0; i < 4; i++)
        *(bf16x8*)(sx + xmm[i] * 520 + xkc[i] * 8) = xr[i];
    }
    __syncthreads();                                   // S_b: sh/sx ready

    // h-part MFMAs (4 chains) on top of pipelined x accumulators
    f32x4 h0 = {0.f,0.f,0.f,0.f}, h1 = {0.f,0.f,0.f,0.f};
    f32x4 h2 = {0.f,0.f,0.f,0.f}, h3 = {0.f,0.f,0.f,0.f};
    {
      const bf16* hrow = sh + rl * 1032;
#pragma unroll
      for (int ks = 0; ks < 32; ks += 4) {
        bf16x8 a0 = *(const bf16x8*)(hrow + ks * 32 + q * 8);
        bf16x8 a1 = *(const bf16x8*)(hrow + (ks + 1) * 32 + q * 8);
        bf16x8 a2 = *(const bf16x8*)(hrow + (ks + 2) * 32 + q * 8);
        bf16x8 a3 = *(const bf16x8*)(hrow + (ks + 3) * 32 + q * 8);
        h0 = __builtin_amdgcn_mfma_f32_16x16x32_bf16(a0, wh[ks],     h0, 0, 0, 0);
        h1 = __builtin_amdgcn_mfma_f32_16x16x32_bf16(a1, wh[ks + 1], h1, 0, 0, 0);
        h2 = __builtin_amdgcn_mfma_f32_16x16x32_bf16(a2, wh[ks + 2], h2, 0, 0, 0);
        h3 = __builtin_amdgcn_mfma_f32_16x16x32_bf16(a3, wh[ks + 3], h3, 0, 0, 0);
      }
    }
    f32x4 pre = ((xa0 + xa1) + (h0 + h1)) + (h2 + h3);

    // activation: lane's gate
    f32x4 av;
    if (gate == 2) {
#pragma unroll
      for (int r = 0; r < 4; r++) {
        float x = fminf(fmaxf(pre[r] + bv, -20.f), 20.f);
        float e = __expf(-2.f * x);
        av[r] = (1.f - e) / (1.f + e);
      }
    } else {
#pragma unroll
      for (int r = 0; r < 4; r++) {
        float x = fminf(fmaxf(pre[r] + bv, -30.f), 30.f);
        av[r] = 1.f / (1.f + __expf(-x));
      }
    }

    // intra-wave gate exchange + pointwise (4x redundant across gates)
    int base = (l & 48) | (l & 3);
    bf16x8 hv8;
#pragma unroll
    for (int r = 0; r < 4; r++) {
      float fg = __shfl(av[r], base,      64);
      float ig = __shfl(av[r], base + 4,  64);
      float gg = __shfl(av[r], base + 8,  64);
      float og = __shfl(av[r], base + 12, 64);
      creg[r] = creg[r] * fg + gg * ig;
      hv8[r] = (bf16)(creg[r] * og);
    }
    // gate-0 lanes deposit h into wave-local LDS, 16 lanes publish 8B each
    if (rl < 4) {
#pragma unroll
      for (int r = 0; r < 4; r++) hw[w][q * 4 + r][rl] = hv8[r];
    }
    if (l < 16) {
      ull v = *(const ull*)&hw[w][l][0];
      __hip_atomic_store((ull*)(wbuf + (size_t)(gb * 16 + l) * 1024 + j0 + w * 4),
                         v, __ATOMIC_RELAXED, __HIP_MEMORY_SCOPE_AGENT);
    }

    // x-part MFMAs for ts+1 — cover the publish-store drain
    if (ts < 511) {
      xa0 = {0.f, 0.f, 0.f, 0.f}; xa1 = {0.f, 0.f, 0.f, 0.f};
      const bf16* xrow = sx + rl * 520;
#pragma unroll
      for (int ks = 0; ks < 16; ks += 2) {
        bf16x8 a0 = *(const bf16x8*)(xrow + ks * 32 + q * 8);
        bf16x8 a1 = *(const bf16x8*)(xrow + (ks + 1) * 32 + q * 8);
        xa0 = __builtin_amdgcn_mfma_f32_16x16x32_bf16(a0, wx[ks], xa0, 0, 0, 0);
        xa1 = __builtin_amdgcn_mfma_f32_16x16x32_bf16(a1, wx[ks + 1], xa1, 0, 0, 0);
      }
    }

    __syncthreads();                                   // S_c: drains publishes
    if (t == 0)
      __hip_atomic_store(flags + wgid, (unsigned)(ts + 1),
                         __ATOMIC_RELAXED, __HIP_MEMORY_SCOPE_AGENT);
  }
}

// ---------------------------------------------------------------------------
// Final logits, fp32 VALU: out[b][v] = sum_k h[b][k]*Wout[k][v] + bout[v].
// ---------------------------------------------------------------------------
__global__ __launch_bounds__(256) void k_final(const bf16* __restrict__ h,
                                               const float* __restrict__ Wout,
                                               const float* __restrict__ boutp,
                                               float* __restrict__ out) {
  int t = threadIdx.x;
  int v = blockIdx.x * 256 + t;
  int b0 = blockIdx.y * 32;
  __shared__ __align__(16) bf16 shf[32 * 1024];
#pragma unroll
  for (int i = 0; i < 16; i++) {
    int c = i * 256 + t;
    int mm = c >> 7, kc = c & 127;
    *(bf16x8*)(shf + mm * 1024 + kc * 8) =
        *(const bf16x8*)(h + (size_t)(b0 + mm) * 1024 + kc * 8);
  }
  __syncthreads();
  float acc[32];
  float bb = boutp[v];
#pragma unroll
  for (int mm = 0; mm < 32; mm++) acc[mm] = bb;
  for (int k = 0; k < 1024; k++) {
    float wv = Wout[(size_t)k * 32000 + v];
#pragma unroll
    for (int mm = 0; mm < 32; mm++) acc[mm] += (float)shf[mm * 1024 + k] * wv;
  }
#pragma unroll
  for (int mm = 0; mm < 32; mm++)
    out[(size_t)(b0 + mm) * 32000 + v] = acc[mm];
}

// ---------------------------------------------------------------------------
// Workspace (bytes), total 45,614,080 (R1 layout):
//   WT    @ 0        : 4096*1536*2  = 12,582,912  (gate-interleaved packed)
//   embB  @ 12582912 : 32000*512*2  = 32,768,000
//   hbuf  @ 45350912 : 2*64*1024*2  =    262,144  (zeroed)
//   flags @ 45613056 : 4 groups * 64 dwords = 1024  (zeroed)
// ---------------------------------------------------------------------------
extern "C" void kernel_launch(void* const* d_in, const int* in_sizes, int n_in,
                              void* d_out, int out_size, void* d_ws, size_t ws_size,
                              hipStream_t stream) {
  const int*   ids   = (const int*)d_in[0];
  const float* embed = (const float*)d_in[1];
  const float* Wf    = (const float*)d_in[2];
  const float* bfp   = (const float*)d_in[3];
  const float* Wi    = (const float*)d_in[4];
  const float* bip   = (const float*)d_in[5];
  const float* Wc    = (const float*)d_in[6];
  const float* bcp   = (const float*)d_in[7];
  const float* Wo    = (const float*)d_in[8];
  const float* bop   = (const float*)d_in[9];
  const float* Wout  = (const float*)d_in[10];
  const float* bout  = (const float*)d_in[11];
  float* out = (float*)d_out;

  char* ws = (char*)d_ws;
  bf16*     WT    = (bf16*)(ws);
  bf16*     embB  = (bf16*)(ws + 12582912ull);
  bf16*     hbuf  = (bf16*)(ws + 45350912ull);
  unsigned* flags = (unsigned*)(ws + 45613056ull);

  k_zero<<<258, 256, 0, stream>>>((unsigned*)(ws + 45350912ull), 65792);
  k_wt<<<dim3(24, 16, 4), 256, 0, stream>>>(Wf, Wi, Wc, Wo, WT);
  k_cvt<<<8000, 256, 0, stream>>>(embed, embB);
  k_lstm<<<256, 256, 0, stream>>>(ids, embB, WT, bfp, bip, bcp, bop, hbuf, flags);
  k_final<<<dim3(125, 2), 256, 0, stream>>>(hbuf, Wout, bout, out);
}

// Round 5
// 2527.778 us; speedup vs baseline: 2.5537x; 2.5537x over previous
//
#include <hip/hip_runtime.h>
#include <math.h>

typedef __bf16 bf16;
typedef unsigned long long ull;
typedef __attribute__((ext_vector_type(8))) __bf16 bf16x8;
typedef __attribute__((ext_vector_type(4))) float f32x4;

__global__ __launch_bounds__(256) void k_zero(unsigned* __restrict__ p, int n) {
  int i = blockIdx.x * 256 + threadIdx.x;
  if (i < n) p[i] = 0u;
}

// Gate-interleaved packed weights:
//   WT[row][k],  row = (j>>2)*16 + g*4 + (j&3),  j in [0,1024), g in [0,4)
// so that MFMA B-fragment n-index = g*4 + (j&3) within a wave's 4-column slice.
__global__ __launch_bounds__(256) void k_wt(const float* __restrict__ Wf,
                                            const float* __restrict__ Wi,
                                            const float* __restrict__ Wc,
                                            const float* __restrict__ Wo,
                                            bf16* __restrict__ WT) {
  __shared__ __align__(16) float tile[64][68];
  int g = blockIdx.z;
  const float* src = g == 0 ? Wf : g == 1 ? Wi : g == 2 ? Wc : Wo;
  int t = threadIdx.x;
  int r0 = blockIdx.x * 64, c0 = blockIdx.y * 64;   // r: k (1536), c: j (1024)
  int r = t >> 2, cs = (t & 3) * 16;
  const f32x4* s = (const f32x4*)(src + (size_t)(r0 + r) * 1024 + c0 + cs);
#pragma unroll
  for (int i = 0; i < 4; i++) *(f32x4*)&tile[r][cs + i * 4] = s[i];
  __syncthreads();
  int c = t >> 2, rs = (t & 3) * 16;
  bf16x8 v0, v1;
#pragma unroll
  for (int i = 0; i < 8; i++) v0[i] = (bf16)tile[rs + i][c];
#pragma unroll
  for (int i = 0; i < 8; i++) v1[i] = (bf16)tile[rs + 8 + i][c];
  int j = c0 + c;
  size_t row = (size_t)(j >> 2) * 16 + g * 4 + (j & 3);
  bf16* d = WT + row * 1536 + r0 + rs;
  *(bf16x8*)d       = v0;
  *(bf16x8*)(d + 8) = v1;
}

__global__ __launch_bounds__(256) void k_cvt(const float* __restrict__ src,
                                             bf16* __restrict__ dst) {
  size_t i = ((size_t)blockIdx.x * 256 + threadIdx.x) * 8;
  f32x4 a = *(const f32x4*)(src + i);
  f32x4 b = *(const f32x4*)(src + i + 4);
  bf16x8 o;
#pragma unroll
  for (int r = 0; r < 4; r++) { o[r] = (bf16)a[r]; o[4 + r] = (bf16)b[r]; }
  *(bf16x8*)(dst + i) = o;
}

// ---------------------------------------------------------------------------
// Persistent LSTM.  256 blocks = 4 batch-groups x 64 column-owner blocks.
// Wave w owns columns j0 + w*4 .. +4, ALL 4 gates (n = gate*4 + col).
//
// Round-5: R1 schedule byte-exact (atomic 8B h loads, per-BLOCK dword flag,
// 1-dword-per-lane poll, x-MFMAs producer-side) with ONE change:
//   EARLY FLAG via LDS election.  Each wave: publish stores ->
//   s_waitcnt vmcnt(0) (wave-local) -> lane0 ds_atomic_add on a block
//   counter; the 4th wave stores the per-block flag.  Flag leaves
//   ~(x-MFMA + S_c convergence + t0 issue) earlier; poll side unchanged.
//   R2/R3/R4 lessons: no sub-dword stores, no poll fan-out, no fences.
// Producer-side neutrality: S_c waited for the same vmcnt(0) anyway; the
// drain moves before the x-MFMAs instead of overlapping them (sum equal).
// hbuf WAR: each wave's vmcnt(0) drains BOTH its publish stores and its
// slab reads of buf[(ts+1)&1]; flag ts+1 therefore still certifies that
// this block's reads completed (same argument as R1, now per-wave).
// Numerics identical (same MFMA order, sum order, activation clamps).
// ---------------------------------------------------------------------------
__global__ __launch_bounds__(256, 1) void k_lstm(const int* __restrict__ ids,
                                                 const bf16* __restrict__ embB,
                                                 const bf16* __restrict__ WT,
                                                 const float* __restrict__ bfp,
                                                 const float* __restrict__ bip,
                                                 const float* __restrict__ bcp,
                                                 const float* __restrict__ bop,
                                                 bf16* __restrict__ hbuf,
                                                 unsigned* __restrict__ flags_all) {
  int blk = blockIdx.x;
  int gb = blk >> 6, wgid = blk & 63, j0 = wgid * 16;
  int t = threadIdx.x, l = t & 63, w = t >> 6;
  int q = l >> 4, rl = l & 15;
  __shared__ __align__(16) bf16 sx[16 * 520];
  __shared__ __align__(16) bf16 sh[16 * 1032];
  __shared__ __align__(16) bf16 hw[4][16][4];
  __shared__ unsigned scnt;

  // weights: packed row = (wgid*4 + w)*16 + rl
  const bf16* wrow = WT + ((size_t)(wgid * 4 + w) * 16 + rl) * 1536;
  bf16x8 wx[16], wh[32];
#pragma unroll
  for (int ks = 0; ks < 16; ++ks) wx[ks] = *(const bf16x8*)(wrow + ks * 32 + q * 8);
#pragma unroll
  for (int ks = 0; ks < 32; ++ks) wh[ks] = *(const bf16x8*)(wrow + 512 + ks * 32 + q * 8);

  int gate = rl >> 2;
  int jcol = j0 + w * 4 + (rl & 3);
  const float* bias_p = gate == 0 ? bfp : gate == 1 ? bip : gate == 2 ? bcp : bop;
  float bv = bias_p[jcol];

  unsigned* flags = flags_all + gb * 64;
  float creg[4] = {0.f, 0.f, 0.f, 0.f};

  // per-thread x-staging geometry: 4 chunks, chunk i at c = i*256 + t
  int xmm[4], xkc[4];
#pragma unroll
  for (int i = 0; i < 4; i++) { int c = i * 256 + t; xmm[i] = c >> 6; xkc[i] = c & 63; }

  int toks[4];
#pragma unroll
  for (int i = 0; i < 4; i++) toks[i] = ids[(gb * 16 + xmm[i]) * 512 + 0];

  // ---- prologue: stage x(0), compute its MFMAs ----
  if (t == 0) scnt = 0u;
  f32x4 xa0 = {0.f, 0.f, 0.f, 0.f}, xa1 = {0.f, 0.f, 0.f, 0.f};
#pragma unroll
  for (int i = 0; i < 4; i++)
    *(bf16x8*)(sx + xmm[i] * 520 + xkc[i] * 8) =
        *(const bf16x8*)(embB + (size_t)toks[i] * 512 + xkc[i] * 8);
#pragma unroll
  for (int i = 0; i < 4; i++) toks[i] = ids[(gb * 16 + xmm[i]) * 512 + 1];
  __syncthreads();
  {
    const bf16* xrow = sx + rl * 520;
#pragma unroll
    for (int ks = 0; ks < 16; ks += 2) {
      bf16x8 a0 = *(const bf16x8*)(xrow + ks * 32 + q * 8);
      bf16x8 a1 = *(const bf16x8*)(xrow + (ks + 1) * 32 + q * 8);
      xa0 = __builtin_amdgcn_mfma_f32_16x16x32_bf16(a0, wx[ks], xa0, 0, 0, 0);
      xa1 = __builtin_amdgcn_mfma_f32_16x16x32_bf16(a1, wx[ks + 1], xa1, 0, 0, 0);
    }
  }
  __syncthreads();   // protect sx before iter-0 overwrite

  for (int ts = 0; ts < 512; ++ts) {
    const bf16* rbuf = hbuf + (ts & 1) * 65536;
    bf16* wbuf = hbuf + ((ts + 1) & 1) * 65536;

    // (1) issue x(ts+1) loads — flag-independent, in flight over poll
    bf16x8 xr[4];
    if (ts < 511) {
#pragma unroll
      for (int i = 0; i < 4; i++)
        xr[i] = *(const bf16x8*)(embB + (size_t)toks[i] * 512 + xkc[i] * 8);
    }

    // (2) all waves wait for producers of h(ts); overlaps xr latency
    if (ts > 0) {
      unsigned tgt = (unsigned)ts;
      for (;;) {
        unsigned v = __hip_atomic_load(flags + l, __ATOMIC_RELAXED,
                                       __HIP_MEMORY_SCOPE_AGENT);
        if (__ballot(v >= tgt) == ~0ull) break;
        __builtin_amdgcn_s_sleep(1);
      }
    }

    // (3) h slab [16][1024] -> regs (paired coherent 8B loads)
    ull ha[8], hb[8];
#pragma unroll
    for (int i = 0; i < 8; i++) {
      int chunk = i * 256 + t;                       // 16B chunks
      int mm = chunk >> 7, kc8 = (chunk & 127) * 8;  // bf16 units
      const ull* gp = (const ull*)(rbuf + (size_t)(gb * 16 + mm) * 1024 + kc8);
      ha[i] = __hip_atomic_load(gp,     __ATOMIC_RELAXED, __HIP_MEMORY_SCOPE_AGENT);
      hb[i] = __hip_atomic_load(gp + 1, __ATOMIC_RELAXED, __HIP_MEMORY_SCOPE_AGENT);
    }

    // (4) prefetch token ids for ts+2
    if (ts < 510) {
#pragma unroll
      for (int i = 0; i < 4; i++) toks[i] = ids[(gb * 16 + xmm[i]) * 512 + ts + 2];
    }

    // (5) regs -> LDS
#pragma unroll
    for (int i = 0; i < 8; i++) {
      int chunk = i * 256 + t;
      int mm = chunk >> 7, kc8 = (chunk & 127) * 8;
      ull* lp = (ull*)(sh + mm * 1032 + kc8);
      lp[0] = ha[i]; lp[1] = hb[i];
    }
    if (ts < 511) {
#pragma unroll
      for (int i = 0; i < 4; i++)
        *(bf16x8*)(sx + xmm[i] * 520 + xkc[i] * 8) = xr[i];
    }
    __syncthreads();                                   // S_b: sh/sx ready

    // h-part MFMAs (4 chains) on top of pipelined x accumulators
    f32x4 h0 = {0.f,0.f,0.f,0.f}, h1 = {0.f,0.f,0.f,0.f};
    f32x4 h2 = {0.f,0.f,0.f,0.f}, h3 = {0.f,0.f,0.f,0.f};
    {
      const bf16* hrow = sh + rl * 1032;
#pragma unroll
      for (int ks = 0; ks < 32; ks += 4) {
        bf16x8 a0 = *(const bf16x8*)(hrow + ks * 32 + q * 8);
        bf16x8 a1 = *(const bf16x8*)(hrow + (ks + 1) * 32 + q * 8);
        bf16x8 a2 = *(const bf16x8*)(hrow + (ks + 2) * 32 + q * 8);
        bf16x8 a3 = *(const bf16x8*)(hrow + (ks + 3) * 32 + q * 8);
        h0 = __builtin_amdgcn_mfma_f32_16x16x32_bf16(a0, wh[ks],     h0, 0, 0, 0);
        h1 = __builtin_amdgcn_mfma_f32_16x16x32_bf16(a1, wh[ks + 1], h1, 0, 0, 0);
        h2 = __builtin_amdgcn_mfma_f32_16x16x32_bf16(a2, wh[ks + 2], h2, 0, 0, 0);
        h3 = __builtin_amdgcn_mfma_f32_16x16x32_bf16(a3, wh[ks + 3], h3, 0, 0, 0);
      }
    }
    f32x4 pre = ((xa0 + xa1) + (h0 + h1)) + (h2 + h3);

    // activation: lane's gate
    f32x4 av;
    if (gate == 2) {
#pragma unroll
      for (int r = 0; r < 4; r++) {
        float x = fminf(fmaxf(pre[r] + bv, -20.f), 20.f);
        float e = __expf(-2.f * x);
        av[r] = (1.f - e) / (1.f + e);
      }
    } else {
#pragma unroll
      for (int r = 0; r < 4; r++) {
        float x = fminf(fmaxf(pre[r] + bv, -30.f), 30.f);
        av[r] = 1.f / (1.f + __expf(-x));
      }
    }

    // intra-wave gate exchange + pointwise (4x redundant across gates)
    int base = (l & 48) | (l & 3);
    bf16x8 hv8;
#pragma unroll
    for (int r = 0; r < 4; r++) {
      float fg = __shfl(av[r], base,      64);
      float ig = __shfl(av[r], base + 4,  64);
      float gg = __shfl(av[r], base + 8,  64);
      float og = __shfl(av[r], base + 12, 64);
      creg[r] = creg[r] * fg + gg * ig;
      hv8[r] = (bf16)(creg[r] * og);
    }
    // gate-0 lanes deposit h into wave-local LDS, 16 lanes publish 8B each
    if (rl < 4) {
#pragma unroll
      for (int r = 0; r < 4; r++) hw[w][q * 4 + r][rl] = hv8[r];
    }
    if (l < 16) {
      ull v = *(const ull*)&hw[w][l][0];
      __hip_atomic_store((ull*)(wbuf + (size_t)(gb * 16 + l) * 1024 + j0 + w * 4),
                         v, __ATOMIC_RELAXED, __HIP_MEMORY_SCOPE_AGENT);
    }

    // EARLY FLAG: wave-local drain of publish stores (S_c would wait for
    // this anyway), then LDS election; 4th wave stores the block flag.
    asm volatile("s_waitcnt vmcnt(0)" ::: "memory");
    if (l == 0) {
      unsigned old = atomicAdd(&scnt, 1u);
      if (old == (unsigned)ts * 4u + 3u)
        __hip_atomic_store(flags + wgid, (unsigned)(ts + 1),
                           __ATOMIC_RELAXED, __HIP_MEMORY_SCOPE_AGENT);
    }
    __builtin_amdgcn_sched_barrier(0);   // pin flag store before MFMA cluster

    // x-part MFMAs for ts+1 (flag already in flight)
    if (ts < 511) {
      xa0 = {0.f, 0.f, 0.f, 0.f}; xa1 = {0.f, 0.f, 0.f, 0.f};
      const bf16* xrow = sx + rl * 520;
#pragma unroll
      for (int ks = 0; ks < 16; ks += 2) {
        bf16x8 a0 = *(const bf16x8*)(xrow + ks * 32 + q * 8);
        bf16x8 a1 = *(const bf16x8*)(xrow + (ks + 1) * 32 + q * 8);
        xa0 = __builtin_amdgcn_mfma_f32_16x16x32_bf16(a0, wx[ks], xa0, 0, 0, 0);
        xa1 = __builtin_amdgcn_mfma_f32_16x16x32_bf16(a1, wx[ks + 1], xa1, 0, 0, 0);
      }
    }

    __syncthreads();                                   // S_c: WAR for sx/sh
  }
}

// ---------------------------------------------------------------------------
// Final logits, fp32 VALU: out[b][v] = sum_k h[b][k]*Wout[k][v] + bout[v].
// ---------------------------------------------------------------------------
__global__ __launch_bounds__(256) void k_final(const bf16* __restrict__ h,
                                               const float* __restrict__ Wout,
                                               const float* __restrict__ boutp,
                                               float* __restrict__ out) {
  int t = threadIdx.x;
  int v = blockIdx.x * 256 + t;
  int b0 = blockIdx.y * 32;
  __shared__ __align__(16) bf16 shf[32 * 1024];
#pragma unroll
  for (int i = 0; i < 16; i++) {
    int c = i * 256 + t;
    int mm = c >> 7, kc = c & 127;
    *(bf16x8*)(shf + mm * 1024 + kc * 8) =
        *(const bf16x8*)(h + (size_t)(b0 + mm) * 1024 + kc * 8);
  }
  __syncthreads();
  float acc[32];
  float bb = boutp[v];
#pragma unroll
  for (int mm = 0; mm < 32; mm++) acc[mm] = bb;
  for (int k = 0; k < 1024; k++) {
    float wv = Wout[(size_t)k * 32000 + v];
#pragma unroll
    for (int mm = 0; mm < 32; mm++) acc[mm] += (float)shf[mm * 1024 + k] * wv;
  }
#pragma unroll
  for (int mm = 0; mm < 32; mm++)
    out[(size_t)(b0 + mm) * 32000 + v] = acc[mm];
}

// ---------------------------------------------------------------------------
// Workspace (bytes), total 45,614,080 (R1 layout):
//   WT    @ 0        : 4096*1536*2  = 12,582,912  (gate-interleaved packed)
//   embB  @ 12582912 : 32000*512*2  = 32,768,000
//   hbuf  @ 45350912 : 2*64*1024*2  =    262,144  (zeroed)
//   flags @ 45613056 : 4 groups * 64 dwords = 1024  (zeroed)
// ---------------------------------------------------------------------------
extern "C" void kernel_launch(void* const* d_in, const int* in_sizes, int n_in,
                              void* d_out, int out_size, void* d_ws, size_t ws_size,
                              hipStream_t stream) {
  const int*   ids   = (const int*)d_in[0];
  const float* embed = (const float*)d_in[1];
  const float* Wf    = (const float*)d_in[2];
  const float* bfp   = (const float*)d_in[3];
  const float* Wi    = (const float*)d_in[4];
  const float* bip   = (const float*)d_in[5];
  const float* Wc    = (const float*)d_in[6];
  const float* bcp   = (const float*)d_in[7];
  const float* Wo    = (const float*)d_in[8];
  const float* bop   = (const float*)d_in[9];
  const float* Wout  = (const float*)d_in[10];
  const float* bout  = (const float*)d_in[11];
  float* out = (float*)d_out;

  char* ws = (char*)d_ws;
  bf16*     WT    = (bf16*)(ws);
  bf16*     embB  = (bf16*)(ws + 12582912ull);
  bf16*     hbuf  = (bf16*)(ws + 45350912ull);
  unsigned* flags = (unsigned*)(ws + 45613056ull);

  k_zero<<<258, 256, 0, stream>>>((unsigned*)(ws + 45350912ull), 65792);
  k_wt<<<dim3(24, 16, 4), 256, 0, stream>>>(Wf, Wi, Wc, Wo, WT);
  k_cvt<<<8000, 256, 0, stream>>>(embed, embB);
  k_lstm<<<256, 256, 0, stream>>>(ids, embB, WT, bfp, bip, bcp, bop, hbuf, flags);
  k_final<<<dim3(125, 2), 256, 0, stream>>>(hbuf, Wout, bout, out);
}